// Round 3
// baseline (2550.659 us; speedup 1.0000x reference)
//
#include <hip/hip_runtime.h>

typedef unsigned short u16;
typedef short s16x8 __attribute__((ext_vector_type(8)));
typedef u16 u16x8 __attribute__((ext_vector_type(8)));
typedef u16 u16x4 __attribute__((ext_vector_type(4)));
typedef float f32x4 __attribute__((ext_vector_type(4)));

#define DEV __device__ __forceinline__

DEV float bf2f(u16 x) { unsigned v = ((unsigned)x) << 16; float f; __builtin_memcpy(&f, &v, 4); return f; }
DEV u16 f2bf(float f) { unsigned u; __builtin_memcpy(&u, &f, 4); u += 0x7FFFu + ((u >> 16) & 1u); return (u16)(u >> 16); }

// ---------------- dtype detector: bf16 data as bf16 maxes ~5; f32 data as bf16 explodes ----------------
__global__ void detect_dtype(const u16* __restrict__ x, int* __restrict__ flag) {
  int tid = threadIdx.x;
  float mx = 0.f;
  for (int i = tid; i < 4096; i += 256) mx = fmaxf(mx, fabsf(bf2f(x[i])));
  __shared__ float red[4];
  int wave = tid >> 6, lane = tid & 63;
  for (int off = 32; off; off >>= 1) mx = fmaxf(mx, __shfl_xor(mx, off));
  if (lane == 0) red[wave] = mx;
  __syncthreads();
  if (tid == 0) {
    mx = fmaxf(fmaxf(red[0], red[1]), fmaxf(red[2], red[3]));
    *flag = (mx > 1e4f) ? 1 : 0;   // 1 = inputs are float32
  }
}

// ---------------- input canonicalizer: src (bf16 or f32 per flag) -> bf16 ----------------
__global__ void convert_in(const void* __restrict__ src, u16* __restrict__ dst, int n,
                           const int* __restrict__ flag) {
  int i = blockIdx.x * 256 + threadIdx.x;
  if (i >= n) return;
  if (*flag) dst[i] = f2bf(((const float*)src)[i]);
  else       dst[i] = ((const u16*)src)[i];
}

// ---------------- BN prep: scale = g*rsqrt(v+eps), shift = b - m*scale ----------------
__global__ void bn_prep(const u16* __restrict__ cbn, float* __restrict__ out) {
  int w = blockIdx.x;
  const u16* bn = cbn + w * 2048;
  int c = threadIdx.x;
  float g = bf2f(bn[c]), be = bf2f(bn[512 + c]), m = bf2f(bn[1024 + c]), v = bf2f(bn[1536 + c]);
  float sc = g * rsqrtf(v + 1e-5f);
  out[w * 1024 + c] = sc;
  out[w * 1024 + 512 + c] = be - m * sc;
}

// ---------------- weight repack (O,I,3,3) -> (O,3,3,I) ----------------
__global__ __launch_bounds__(256) void repack_w3(const u16* __restrict__ w, u16* __restrict__ wr,
                                                 int I, int Ishift) {
  size_t idx = ((size_t)blockIdx.x * 256 + threadIdx.x) * 8;
  int i0 = (int)(idx & (size_t)(I - 1));
  int t = (int)(idx >> Ishift);
  int o = t / 9, kk = t - o * 9;
  u16x8 v;
#pragma unroll
  for (int j = 0; j < 8; ++j) v[j] = w[((size_t)o * I + i0 + j) * 9 + kk];
  *(u16x8*)&wr[idx] = v;
}

// ---------------- x NCHW -> padded NHWC (B,66,66,2048), borders pre-zeroed ----------------
__global__ __launch_bounds__(256) void pad_nchw(const u16* __restrict__ x, u16* __restrict__ xpad) {
  __shared__ u16 t[64][72];
  int c0 = blockIdx.x * 64, h = blockIdx.y, b = blockIdx.z;
  int tid = threadIdx.x;
#pragma unroll
  for (int i = 0; i < 2; ++i) {
    int idx = i * 256 + tid;
    int cc = idx >> 3, ww = (idx & 7) * 8;
    u16x8 v = *(const u16x8*)&x[(((size_t)(b * 2048 + c0 + cc) * 64) + h) * 64 + ww];
    *(u16x8*)&t[cc][ww] = v;
  }
  __syncthreads();
#pragma unroll
  for (int i = 0; i < 2; ++i) {
    int idx = i * 256 + tid;
    int ww = idx >> 3, cc = (idx & 7) * 8;
    u16x8 v;
#pragma unroll
    for (int j = 0; j < 8; ++j) v[j] = t[cc + j][ww];
    *(u16x8*)&xpad[(((size_t)b * 66 + h + 1) * 66 + ww + 1) * 2048 + c0 + cc] = v;
  }
}

// ---------------- generic bf16 transpose (R,C)->(C,R) per batch ----------------
__global__ __launch_bounds__(256) void transpose64(const u16* __restrict__ src, u16* __restrict__ dst,
                                                   int R, int C) {
  __shared__ u16 t[64][72];
  int r0 = blockIdx.x * 64, c0 = blockIdx.y * 64;
  const u16* s = src + (size_t)blockIdx.z * R * C;
  u16* d = dst + (size_t)blockIdx.z * R * C;
  int tid = threadIdx.x;
#pragma unroll
  for (int i = 0; i < 2; ++i) {
    int idx = i * 256 + tid;
    int rr = idx >> 3, cc = (idx & 7) * 8;
    u16x8 v = *(const u16x8*)&s[(size_t)(r0 + rr) * C + c0 + cc];
    *(u16x8*)&t[rr][cc] = v;
  }
  __syncthreads();
#pragma unroll
  for (int i = 0; i < 2; ++i) {
    int idx = i * 256 + tid;
    int cc = idx >> 3, rr = (idx & 7) * 8;
    u16x8 v;
#pragma unroll
    for (int j = 0; j < 8; ++j) v[j] = t[rr + j][cc];
    *(u16x8*)&d[(size_t)(c0 + cc) * R + r0 + rr] = v;
  }
}

// ---------------- unified NT GEMM: C[m,n] = sum_k A[m,k]*B[n,k] ----------------
// EPI: 0 = bf16 store (+bias, *rowscale) ; 1 = bf16 transposed store (+bias,*rowscale)
//      2 = fp32 store ; 3 = alpha*acc + residual -> padded NHWC bf16 store
struct GemmP {
  const u16* A; const u16* B;
  long aBatch, bBatch;
  int M, N, K;
  u16* out; long outBatch; int ldOut;
  const u16* bias;
  const u16* rowscale;
  const u16* residual; long resBatch; int ldRes;
  const u16* alphaPtr;
  float* outF; long outFBatch;
};

template <int BM, int BN, int EPI>
__global__ __launch_bounds__(256) void gemm_nt(GemmP p) {
  __shared__ u16 lA[BM * 32], lB[BN * 32];
  const int tid = threadIdx.x;
  const int bz = blockIdx.z;
  const int m0 = blockIdx.x * BM, n0 = blockIdx.y * BN;
  const u16* A = p.A + (size_t)bz * p.aBatch;
  const u16* Bp = p.B + (size_t)bz * p.bBatch;
  const int wave = tid >> 6, lane = tid & 63;
  const int quad = lane >> 4, r16 = lane & 15;
  const int wm = (wave >> 1) * (BM / 2), wn = (wave & 1) * (BN / 2);
  constexpr int TM = BM / 32, TN = BN / 32;
  f32x4 acc[TM][TN] = {};
  const int srow = tid >> 2, sch = (tid & 3) * 8;
  const int K = p.K;
  for (int k0 = 0; k0 < K; k0 += 32) {
    u16x8 ra[BM / 64], rb[BN / 64];
#pragma unroll
    for (int i = 0; i < BM / 64; ++i)
      ra[i] = *(const u16x8*)&A[(size_t)(m0 + i * 64 + srow) * K + k0 + sch];
#pragma unroll
    for (int i = 0; i < BN / 64; ++i)
      rb[i] = *(const u16x8*)&Bp[(size_t)(n0 + i * 64 + srow) * K + k0 + sch];
    __syncthreads();
#pragma unroll
    for (int i = 0; i < BM / 64; ++i) *(u16x8*)&lA[i * 2048 + tid * 8] = ra[i];
#pragma unroll
    for (int i = 0; i < BN / 64; ++i) *(u16x8*)&lB[i * 2048 + tid * 8] = rb[i];
    __syncthreads();
    s16x8 av[TM], bv[TN];
#pragma unroll
    for (int t = 0; t < TM; ++t) av[t] = *(const s16x8*)&lA[(wm + t * 16 + r16) * 32 + quad * 8];
#pragma unroll
    for (int t = 0; t < TN; ++t) bv[t] = *(const s16x8*)&lB[(wn + t * 16 + r16) * 32 + quad * 8];
#pragma unroll
    for (int i = 0; i < TM; ++i)
#pragma unroll
      for (int j = 0; j < TN; ++j)
        acc[i][j] = __builtin_amdgcn_mfma_f32_16x16x32_bf16(av[i], bv[j], acc[i][j], 0, 0, 0);
  }
  float alpha = 0.f;
  if (EPI == 3) alpha = bf2f(p.alphaPtr[0]);
#pragma unroll
  for (int i = 0; i < TM; ++i) {
#pragma unroll
    for (int j = 0; j < TN; ++j) {
      const int nn = n0 + wn + j * 16 + r16;
      float bia = 0.f;
      if ((EPI == 0 || EPI == 1) && p.bias) bia = bf2f(p.bias[nn]);
#pragma unroll
      for (int r = 0; r < 4; ++r) {
        const int mm = m0 + wm + i * 16 + quad * 4 + r;
        float v = acc[i][j][r];
        if (EPI == 0) {
          v += bia;
          if (p.rowscale) v *= bf2f(p.rowscale[mm]);
          p.out[(size_t)bz * p.outBatch + (size_t)mm * p.ldOut + nn] = f2bf(v);
        } else if (EPI == 1) {
          v += bia;
          if (p.rowscale) v *= bf2f(p.rowscale[mm]);
          p.out[(size_t)bz * p.outBatch + (size_t)nn * p.ldOut + mm] = f2bf(v);
        } else if (EPI == 2) {
          p.outF[(size_t)bz * p.outFBatch + (size_t)mm * p.ldOut + nn] = v;
        } else {
          float res = bf2f(p.residual[(size_t)bz * p.resBatch + (size_t)mm * p.ldRes + nn]);
          v = alpha * v + res;
          const int py = mm >> 6, px = mm & 63;
          p.out[(size_t)bz * p.outBatch + ((size_t)(py + 1) * 66 + (px + 1)) * p.ldOut + nn] = f2bf(v);
        }
      }
    }
  }
}

// ---------------- 3x3 conv (implicit GEMM) + BN + ReLU, NHWC padded input ----------------
template <int CIN>
__global__ __launch_bounds__(256) void conv3x3_k(const u16* __restrict__ xpad, const u16* __restrict__ wr,
                                                 const float* __restrict__ scale,
                                                 const float* __restrict__ shift,
                                                 u16* __restrict__ out) {
  __shared__ u16 lA[128 * 32], lB[128 * 32];
  const int tid = threadIdx.x;
  const int b = blockIdx.z, m0 = blockIdx.x * 128, n0 = blockIdx.y * 128;
  const int wave = tid >> 6, lane = tid & 63;
  const int quad = lane >> 4, r16 = lane & 15;
  const int wm = (wave >> 1) * 64, wn = (wave & 1) * 64;
  f32x4 acc[4][4] = {};
  const int srow = tid >> 2, sch = (tid & 3) * 8;
  const int p0 = m0 + srow, p1 = m0 + 64 + srow;
  const int p0y = p0 >> 6, p0x = p0 & 63, p1y = p1 >> 6, p1x = p1 & 63;
  for (int kh = 0; kh < 3; ++kh) {
    for (int kw = 0; kw < 3; ++kw) {
      const int kk = kh * 3 + kw;
      const size_t ga0 = (((size_t)b * 66 + p0y + kh) * 66 + p0x + kw) * CIN + sch;
      const size_t ga1 = (((size_t)b * 66 + p1y + kh) * 66 + p1x + kw) * CIN + sch;
      const size_t gb0 = ((size_t)(n0 + srow) * 9 + kk) * CIN + sch;
      const size_t gb1 = ((size_t)(n0 + 64 + srow) * 9 + kk) * CIN + sch;
      for (int c = 0; c < CIN; c += 32) {
        u16x8 ra0 = *(const u16x8*)&xpad[ga0 + c];
        u16x8 ra1 = *(const u16x8*)&xpad[ga1 + c];
        u16x8 rb0 = *(const u16x8*)&wr[gb0 + c];
        u16x8 rb1 = *(const u16x8*)&wr[gb1 + c];
        __syncthreads();
        *(u16x8*)&lA[tid * 8] = ra0;
        *(u16x8*)&lA[2048 + tid * 8] = ra1;
        *(u16x8*)&lB[tid * 8] = rb0;
        *(u16x8*)&lB[2048 + tid * 8] = rb1;
        __syncthreads();
        s16x8 av[4], bv[4];
#pragma unroll
        for (int t = 0; t < 4; ++t) av[t] = *(const s16x8*)&lA[(wm + t * 16 + r16) * 32 + quad * 8];
#pragma unroll
        for (int t = 0; t < 4; ++t) bv[t] = *(const s16x8*)&lB[(wn + t * 16 + r16) * 32 + quad * 8];
#pragma unroll
        for (int i = 0; i < 4; ++i)
#pragma unroll
          for (int j = 0; j < 4; ++j)
            acc[i][j] = __builtin_amdgcn_mfma_f32_16x16x32_bf16(av[i], bv[j], acc[i][j], 0, 0, 0);
      }
    }
  }
#pragma unroll
  for (int i = 0; i < 4; ++i) {
#pragma unroll
    for (int j = 0; j < 4; ++j) {
      const int nn = n0 + wn + j * 16 + r16;
      const float s = scale[nn], sh = shift[nn];
#pragma unroll
      for (int r = 0; r < 4; ++r) {
        const int mm = m0 + wm + i * 16 + quad * 4 + r;
        float v = fmaxf(acc[i][j][r] * s + sh, 0.f);
        out[((size_t)b * 4096 + mm) * 512 + nn] = f2bf(v);
      }
    }
  }
}

// ---------------- softmax over rows of 4096 (fp32 in, bf16 out) ----------------
__global__ __launch_bounds__(256) void softmax4096(const float* __restrict__ S, u16* __restrict__ P) {
  int row = blockIdx.x, tid = threadIdx.x;
  const float* sr = S + (size_t)row * 4096;
  f32x4 v[4];
  float mx = -3.4e38f;
#pragma unroll
  for (int i = 0; i < 4; ++i) {
    v[i] = *(const f32x4*)&sr[(i * 256 + tid) * 4];
    mx = fmaxf(mx, fmaxf(fmaxf(v[i][0], v[i][1]), fmaxf(v[i][2], v[i][3])));
  }
  __shared__ float red[8];
  int wave = tid >> 6, lane = tid & 63;
  for (int off = 32; off; off >>= 1) mx = fmaxf(mx, __shfl_xor(mx, off));
  if (lane == 0) red[wave] = mx;
  __syncthreads();
  mx = fmaxf(fmaxf(red[0], red[1]), fmaxf(red[2], red[3]));
  float sum = 0.f;
#pragma unroll
  for (int i = 0; i < 4; ++i)
#pragma unroll
    for (int j = 0; j < 4; ++j) { float e = __expf(v[i][j] - mx); v[i][j] = e; sum += e; }
  for (int off = 32; off; off >>= 1) sum += __shfl_xor(sum, off);
  if (lane == 0) red[4 + wave] = sum;
  __syncthreads();
  sum = red[4] + red[5] + red[6] + red[7];
  float inv = 1.f / sum;
  u16* pr = P + (size_t)row * 4096;
#pragma unroll
  for (int i = 0; i < 4; ++i) {
    u16x4 ov;
#pragma unroll
    for (int j = 0; j < 4; ++j) ov[j] = f2bf(v[i][j] * inv);
    *(u16x4*)&pr[(i * 256 + tid) * 4] = ov;
  }
}

// ---------------- CAM softmax: L = rowmax - S, softmax(L); rows of 512 ----------------
__global__ __launch_bounds__(256) void softmax_cam(const float* __restrict__ S, u16* __restrict__ P) {
  int row = blockIdx.x, tid = threadIdx.x;
  const float* sr = S + (size_t)row * 512;
  float a = sr[tid], b = sr[tid + 256];
  __shared__ float red[12];
  int wave = tid >> 6, lane = tid & 63;
  float mx = fmaxf(a, b);
  for (int off = 32; off; off >>= 1) mx = fmaxf(mx, __shfl_xor(mx, off));
  if (lane == 0) red[wave] = mx;
  __syncthreads();
  float M1 = fmaxf(fmaxf(red[0], red[1]), fmaxf(red[2], red[3]));
  float mn = fminf(a, b);
  for (int off = 32; off; off >>= 1) mn = fminf(mn, __shfl_xor(mn, off));
  if (lane == 0) red[4 + wave] = mn;
  __syncthreads();
  float m2 = M1 - fminf(fminf(red[4], red[5]), fminf(red[6], red[7]));
  float e0 = __expf((M1 - a) - m2), e1 = __expf((M1 - b) - m2);
  float sum = e0 + e1;
  for (int off = 32; off; off >>= 1) sum += __shfl_xor(sum, off);
  if (lane == 0) red[8 + wave] = sum;
  __syncthreads();
  sum = red[8] + red[9] + red[10] + red[11];
  float inv = 1.f / sum;
  P[(size_t)row * 512 + tid] = f2bf(e0 * inv);
  P[(size_t)row * 512 + tid + 256] = f2bf(e1 * inv);
}

// ---------------- final three 19-class 1x1 convs (writes NCHW d_out, dtype per flag) ----------------
__global__ __launch_bounds__(256) void final_out_k(const u16* __restrict__ fp2, const u16* __restrict__ fc2,
                                                   const u16* __restrict__ fv2,
                                                   const u16* ow, const u16* ob, const u16* pw,
                                                   const u16* pb, const u16* cw, const u16* cb,
                                                   void* __restrict__ out, const int* __restrict__ flag) {
  __shared__ float wl[19 * 512];
  int tid = threadIdx.x, which = blockIdx.y;
  const u16* W = which == 0 ? ow : which == 1 ? pw : cw;
  const u16* Bb = which == 0 ? ob : which == 1 ? pb : cb;
  for (int i = tid; i < 19 * 512; i += 256) wl[i] = bf2f(W[i]);
  __syncthreads();
  int pix = blockIdx.x * 256 + tid;
  size_t rb = (size_t)pix * 512;
  float acc[19];
#pragma unroll
  for (int o = 0; o < 19; ++o) acc[o] = 0.f;
  for (int c = 0; c < 512; c += 8) {
    float xs[8];
    if (which == 0) {
      u16x8 a = *(const u16x8*)&fp2[rb + c];
      u16x8 d = *(const u16x8*)&fc2[rb + c];
      u16x8 e = *(const u16x8*)&fv2[rb + c];
#pragma unroll
      for (int j = 0; j < 8; ++j) xs[j] = bf2f(a[j]) + bf2f(d[j]) + bf2f(e[j]);
    } else {
      const u16* src = which == 1 ? fp2 : fc2;
      u16x8 a = *(const u16x8*)&src[rb + c];
#pragma unroll
      for (int j = 0; j < 8; ++j) xs[j] = bf2f(a[j]);
    }
#pragma unroll
    for (int o = 0; o < 19; ++o) {
      const float* wv = &wl[o * 512 + c];
#pragma unroll
      for (int j = 0; j < 8; ++j) acc[o] += xs[j] * wv[j];
    }
  }
  int b = pix >> 12, n = pix & 4095;
  const int isF32 = *flag;
#pragma unroll
  for (int o = 0; o < 19; ++o) {
    size_t idx = (size_t)which * 155648 + ((size_t)(b * 19 + o)) * 4096 + n;
    float v = acc[o] + bf2f(Bb[o]);
    if (isF32) ((float*)out)[idx] = v;
    else ((u16*)out)[idx] = f2bf(v);
  }
}

// ---------------- workspace layout (bytes) ----------------
static const size_t OFF_XPAD  = 0;          // 35,684,352 (phase 1)
static const size_t OFF_WRB   = 35684352;   // 18,874,368 (phase 1)
static const size_t OFF_ARENA = 54558720;   // 33,554,432 conversion arena (aliases S-tail/P-head when dead)
static const size_t OFF_S     = 0;          // 67,108,864 fp32 (PAM phase)
static const size_t OFF_P     = 67108864;   // 33,554,432
static const size_t OFF_FP1   = 100663296;
static const size_t OFF_FC1   = 109051904;
static const size_t OFF_FV1   = 117440512;
static const size_t OFF_FC1T  = 125829120;
static const size_t OFF_QT    = 134217728;
static const size_t OFF_KT    = 135266304;
static const size_t OFF_VT    = 136314880;
static const size_t OFF_PADP  = 144703488;
static const size_t OFF_PADC  = 153624576;
static const size_t OFF_PADV  = 162545664;
static const size_t OFF_FP2   = 171466752;
static const size_t OFF_FC2   = 179855360;
static const size_t OFF_FV2   = 188243968;
static const size_t OFF_WRS   = 196632576;
static const size_t OFF_SC    = 201351168;
static const size_t OFF_PC    = 203448320;
static const size_t OFF_BN    = 204496896;
static const size_t OFF_FLAG  = 204521472;
static const size_t OFF_SMALL = 204521728;  // u16 element base for converted small inputs
// small-block element offsets (u16):
static const size_t SO_CBN    = 0;        // 6*2048
static const size_t SO_PWB    = 12288;    // 32768
static const size_t SO_PBB    = 45056;    // 64
static const size_t SO_PWC    = 45120;    // 32768
static const size_t SO_PBC    = 77888;    // 64
static const size_t SO_PWD    = 77952;    // 262144
static const size_t SO_PBD    = 340096;   // 512
static const size_t SO_PAL    = 340608;   // 16
static const size_t SO_CBETA  = 340624;   // 16
static const size_t SO_VWB    = 340640;   // 32768
static const size_t SO_VBB    = 373408;   // 64
static const size_t SO_VWC    = 373472;   // 32768
static const size_t SO_VBC    = 406240;   // 64
static const size_t SO_VWD    = 406304;   // 262144
static const size_t SO_VBD    = 668448;   // 512
static const size_t SO_VAL    = 668960;   // 16
static const size_t SO_OW     = 668976;   // 9728
static const size_t SO_OB     = 678704;   // 32
static const size_t SO_PW3    = 678736;   // 9728
static const size_t SO_PB3    = 688464;   // 32
static const size_t SO_CW3    = 688496;   // 9728
static const size_t SO_CB3    = 698224;   // 32
static const size_t SO_LFM    = 698256;   // 4096
static const size_t SO_END    = 702352;
static const size_t WS_NEEDED = OFF_SMALL + SO_END * 2;  // 205,926,432

extern "C" void kernel_launch(void* const* d_in, const int* in_sizes, int n_in,
                              void* d_out, int out_size, void* d_ws, size_t ws_size,
                              hipStream_t stream) {
  if (ws_size < WS_NEEDED) return;  // diagnostic signature: output stays 0
  (void)in_sizes; (void)n_in; (void)out_size;

  char* ws = (char*)d_ws;
  u16* xpad   = (u16*)(ws + OFF_XPAD);
  u16* wrB    = (u16*)(ws + OFF_WRB);
  u16* arena  = (u16*)(ws + OFF_ARENA);
  float* S    = (float*)(ws + OFF_S);
  u16* P      = (u16*)(ws + OFF_P);
  u16* fp1    = (u16*)(ws + OFF_FP1);
  u16* fc1    = (u16*)(ws + OFF_FC1);
  u16* fv1    = (u16*)(ws + OFF_FV1);
  u16* fc1T   = (u16*)(ws + OFF_FC1T);
  u16* qt     = (u16*)(ws + OFF_QT);
  u16* kt     = (u16*)(ws + OFF_KT);
  u16* vT     = (u16*)(ws + OFF_VT);
  u16* padP   = (u16*)(ws + OFF_PADP);
  u16* padC   = (u16*)(ws + OFF_PADC);
  u16* padV   = (u16*)(ws + OFF_PADV);
  u16* fp2    = (u16*)(ws + OFF_FP2);
  u16* fc2    = (u16*)(ws + OFF_FC2);
  u16* fv2    = (u16*)(ws + OFF_FV2);
  u16* wrS    = (u16*)(ws + OFF_WRS);
  float* Sc   = (float*)(ws + OFF_SC);
  u16* Pc     = (u16*)(ws + OFF_PC);
  float* bnb  = (float*)(ws + OFF_BN);
  int* flag   = (int*)(ws + OFF_FLAG);
  u16* sm     = (u16*)(ws + OFF_SMALL);

  // ---- dtype detect + canonicalize all inputs to bf16 ----
  detect_dtype<<<1, 256, 0, stream>>>((const u16*)d_in[0], flag);
  auto cv = [&](int i, u16* dst, int n) {
    convert_in<<<(n + 255) / 256, 256, 0, stream>>>(d_in[i], dst, n, flag);
  };
  // bn packs in slot order p1,c1,v1,p2,c2,v2
  cv(3,  sm + SO_CBN + 0 * 2048, 2048);
  cv(7,  sm + SO_CBN + 1 * 2048, 2048);
  cv(11, sm + SO_CBN + 2 * 2048, 2048);
  cv(5,  sm + SO_CBN + 3 * 2048, 2048);
  cv(9,  sm + SO_CBN + 4 * 2048, 2048);
  cv(13, sm + SO_CBN + 5 * 2048, 2048);
  cv(14, sm + SO_PWB, 32768);  cv(15, sm + SO_PBB, 64);
  cv(16, sm + SO_PWC, 32768);  cv(17, sm + SO_PBC, 64);
  cv(18, sm + SO_PWD, 262144); cv(19, sm + SO_PBD, 512);
  cv(20, sm + SO_PAL, 1);      cv(21, sm + SO_CBETA, 1);
  cv(22, sm + SO_VWB, 32768);  cv(23, sm + SO_VBB, 64);
  cv(24, sm + SO_VWC, 32768);  cv(25, sm + SO_VBC, 64);
  cv(26, sm + SO_VWD, 262144); cv(27, sm + SO_VBD, 512);
  cv(28, sm + SO_VAL, 1);
  cv(29, sm + SO_OW, 9728);    cv(30, sm + SO_OB, 19);
  cv(31, sm + SO_PW3, 9728);   cv(32, sm + SO_PB3, 19);
  cv(33, sm + SO_CW3, 9728);   cv(34, sm + SO_CB3, 19);
  cv(1,  sm + SO_LFM, 4096);

  bn_prep<<<6, 512, 0, stream>>>(sm + SO_CBN, bnb);

  // ---- x -> padded NHWC ----
  cv(0, arena, 16777216);
  hipMemsetAsync(xpad, 0, 35684352, stream);
  pad_nchw<<<dim3(32, 64, 2), 256, 0, stream>>>(arena, xpad);

  // ---- stage 1: three 2048->512 conv+bn+relu ----
  cv(2, arena, 9437184);
  repack_w3<<<4608, 256, 0, stream>>>(arena, wrB, 2048, 11);
  conv3x3_k<2048><<<dim3(32, 4, 2), 256, 0, stream>>>(xpad, wrB, bnb + 0 * 1024, bnb + 0 * 1024 + 512, fp1);
  cv(6, arena, 9437184);
  repack_w3<<<4608, 256, 0, stream>>>(arena, wrB, 2048, 11);
  conv3x3_k<2048><<<dim3(32, 4, 2), 256, 0, stream>>>(xpad, wrB, bnb + 1 * 1024, bnb + 1 * 1024 + 512, fc1);
  cv(10, arena, 9437184);
  repack_w3<<<4608, 256, 0, stream>>>(arena, wrB, 2048, 11);
  conv3x3_k<2048><<<dim3(32, 4, 2), 256, 0, stream>>>(xpad, wrB, bnb + 2 * 1024, bnb + 2 * 1024 + 512, fv1);

  // ---- PAM (shared for pam / vfam) ----
  auto runPam = [&](const u16* src, const u16* wb, const u16* bb, const u16* wck, const u16* bck,
                    const u16* wd, const u16* bd, const u16* alphaP, const u16* rs, u16* padOut) {
    GemmP g{};
    g.A = src; g.aBatch = 2097152; g.B = wb; g.bBatch = 0; g.M = 4096; g.N = 64; g.K = 512;
    g.out = qt; g.outBatch = 262144; g.ldOut = 64; g.bias = bb; g.rowscale = rs;
    gemm_nt<128, 64, 0><<<dim3(32, 1, 2), 256, 0, stream>>>(g);
    g.B = wck; g.bias = bck; g.out = kt;
    gemm_nt<128, 64, 0><<<dim3(32, 1, 2), 256, 0, stream>>>(g);
    GemmP gv{};
    gv.A = src; gv.aBatch = 2097152; gv.B = wd; gv.bBatch = 0; gv.M = 4096; gv.N = 512; gv.K = 512;
    gv.out = vT; gv.outBatch = 2097152; gv.ldOut = 4096; gv.bias = bd; gv.rowscale = rs;
    gemm_nt<128, 128, 1><<<dim3(32, 4, 2), 256, 0, stream>>>(gv);
    hipMemsetAsync(padOut, 0, 8921088, stream);
    for (int b = 0; b < 2; ++b) {
      GemmP gs{};
      gs.A = qt + (size_t)b * 262144; gs.B = kt + (size_t)b * 262144;
      gs.M = 4096; gs.N = 4096; gs.K = 64;
      gs.outF = S; gs.outFBatch = 0; gs.ldOut = 4096;
      gemm_nt<128, 128, 2><<<dim3(32, 32, 1), 256, 0, stream>>>(gs);
      softmax4096<<<4096, 256, 0, stream>>>(S, P);
      GemmP gf{};
      gf.A = P; gf.aBatch = 0; gf.B = vT + (size_t)b * 2097152; gf.bBatch = 0;
      gf.M = 4096; gf.N = 512; gf.K = 4096;
      gf.out = padOut + (size_t)b * 2230272; gf.outBatch = 0; gf.ldOut = 512;
      gf.residual = src + (size_t)b * 2097152; gf.resBatch = 0; gf.ldRes = 512;
      gf.alphaPtr = alphaP;
      gemm_nt<128, 128, 3><<<dim3(32, 4, 1), 256, 0, stream>>>(gf);
    }
  };
  runPam(fp1, sm + SO_PWB, sm + SO_PBB, sm + SO_PWC, sm + SO_PBC, sm + SO_PWD, sm + SO_PBD,
         sm + SO_PAL, nullptr, padP);
  runPam(fv1, sm + SO_VWB, sm + SO_VBB, sm + SO_VWC, sm + SO_VBC, sm + SO_VWD, sm + SO_VBD,
         sm + SO_VAL, sm + SO_LFM, padV);

  // ---- CAM ----
  transpose64<<<dim3(64, 8, 2), 256, 0, stream>>>(fc1, fc1T, 4096, 512);
  {
    GemmP g{};
    g.A = fc1T; g.aBatch = 2097152; g.B = fc1T; g.bBatch = 2097152;
    g.M = 512; g.N = 512; g.K = 4096;
    g.outF = Sc; g.outFBatch = 262144; g.ldOut = 512;
    gemm_nt<64, 64, 2><<<dim3(8, 8, 2), 256, 0, stream>>>(g);
  }
  softmax_cam<<<1024, 256, 0, stream>>>(Sc, Pc);
  hipMemsetAsync(padC, 0, 8921088, stream);
  {
    GemmP g{};
    g.A = fc1; g.aBatch = 2097152; g.B = Pc; g.bBatch = 262144;
    g.M = 4096; g.N = 512; g.K = 512;
    g.out = padC; g.outBatch = 2230272; g.ldOut = 512;
    g.residual = fc1; g.resBatch = 2097152; g.ldRes = 512;
    g.alphaPtr = sm + SO_CBETA;
    gemm_nt<128, 128, 3><<<dim3(32, 4, 2), 256, 0, stream>>>(g);
  }

  // ---- stage 2: three 512->512 conv+bn+relu ----
  cv(4, arena, 2359296);
  repack_w3<<<1152, 256, 0, stream>>>(arena, wrS, 512, 9);
  conv3x3_k<512><<<dim3(32, 4, 2), 256, 0, stream>>>(padP, wrS, bnb + 3 * 1024, bnb + 3 * 1024 + 512, fp2);
  cv(8, arena, 2359296);
  repack_w3<<<1152, 256, 0, stream>>>(arena, wrS, 512, 9);
  conv3x3_k<512><<<dim3(32, 4, 2), 256, 0, stream>>>(padC, wrS, bnb + 4 * 1024, bnb + 4 * 1024 + 512, fc2);
  cv(12, arena, 2359296);
  repack_w3<<<1152, 256, 0, stream>>>(arena, wrS, 512, 9);
  conv3x3_k<512><<<dim3(32, 4, 2), 256, 0, stream>>>(padV, wrS, bnb + 5 * 1024, bnb + 5 * 1024 + 512, fv2);

  // ---- final 1x1 convs -> d_out (fusion_out, p_out, c_out) ----
  final_out_k<<<dim3(32, 3), 256, 0, stream>>>(fp2, fc2, fv2, sm + SO_OW, sm + SO_OB,
                                               sm + SO_PW3, sm + SO_PB3, sm + SO_CW3, sm + SO_CB3,
                                               d_out, flag);
}

// Round 6
// 1796.681 us; speedup vs baseline: 1.4197x; 1.4197x over previous
//
#include <hip/hip_runtime.h>

typedef unsigned short u16;
typedef short s16x8 __attribute__((ext_vector_type(8)));
typedef u16 u16x8 __attribute__((ext_vector_type(8)));
typedef u16 u16x4 __attribute__((ext_vector_type(4)));
typedef float f32x4 __attribute__((ext_vector_type(4)));

#define DEV __device__ __forceinline__

DEV float bf2f(u16 x) { unsigned v = ((unsigned)x) << 16; float f; __builtin_memcpy(&f, &v, 4); return f; }
DEV u16 f2bf(float f) { unsigned u; __builtin_memcpy(&u, &f, 4); u += 0x7FFFu + ((u >> 16) & 1u); return (u16)(u >> 16); }

// ---------------- dtype detector: bf16 data as bf16 maxes ~5; f32 data as bf16 explodes ----------------
__global__ void detect_dtype(const u16* __restrict__ x, int* __restrict__ flag) {
  int tid = threadIdx.x;
  float mx = 0.f;
  for (int i = tid; i < 4096; i += 256) mx = fmaxf(mx, fabsf(bf2f(x[i])));
  __shared__ float red[4];
  int wave = tid >> 6, lane = tid & 63;
  for (int off = 32; off; off >>= 1) mx = fmaxf(mx, __shfl_xor(mx, off));
  if (lane == 0) red[wave] = mx;
  __syncthreads();
  if (tid == 0) {
    mx = fmaxf(fmaxf(red[0], red[1]), fmaxf(red[2], red[3]));
    *flag = (mx > 1e4f) ? 1 : 0;   // 1 = inputs are float32
  }
}

// ---------------- input canonicalizer: src (bf16 or f32 per flag) -> bf16 ----------------
__global__ void convert_in(const void* __restrict__ src, u16* __restrict__ dst, int n,
                           const int* __restrict__ flag) {
  int i = blockIdx.x * 256 + threadIdx.x;
  if (i >= n) return;
  if (*flag) dst[i] = f2bf(((const float*)src)[i]);
  else       dst[i] = ((const u16*)src)[i];
}

// ---------------- BN prep: scale = g*rsqrt(v+eps), shift = b - m*scale ----------------
__global__ void bn_prep(const u16* __restrict__ cbn, float* __restrict__ out) {
  int w = blockIdx.x;
  const u16* bn = cbn + w * 2048;
  int c = threadIdx.x;
  float g = bf2f(bn[c]), be = bf2f(bn[512 + c]), m = bf2f(bn[1024 + c]), v = bf2f(bn[1536 + c]);
  float sc = g * rsqrtf(v + 1e-5f);
  out[w * 1024 + c] = sc;
  out[w * 1024 + 512 + c] = be - m * sc;
}

// ---------------- weight repack (O,I,3,3) -> (O,3,3,I) ----------------
__global__ __launch_bounds__(256) void repack_w3(const u16* __restrict__ w, u16* __restrict__ wr,
                                                 int I, int Ishift) {
  size_t idx = ((size_t)blockIdx.x * 256 + threadIdx.x) * 8;
  int i0 = (int)(idx & (size_t)(I - 1));
  int t = (int)(idx >> Ishift);
  int o = t / 9, kk = t - o * 9;
  u16x8 v;
#pragma unroll
  for (int j = 0; j < 8; ++j) v[j] = w[((size_t)o * I + i0 + j) * 9 + kk];
  *(u16x8*)&wr[idx] = v;
}

// ---------------- x NCHW -> padded NHWC (B,66,66,2048), borders pre-zeroed ----------------
__global__ __launch_bounds__(256) void pad_nchw(const u16* __restrict__ x, u16* __restrict__ xpad) {
  __shared__ u16 t[64][72];
  int c0 = blockIdx.x * 64, h = blockIdx.y, b = blockIdx.z;
  int tid = threadIdx.x;
#pragma unroll
  for (int i = 0; i < 2; ++i) {
    int idx = i * 256 + tid;
    int cc = idx >> 3, ww = (idx & 7) * 8;
    u16x8 v = *(const u16x8*)&x[(((size_t)(b * 2048 + c0 + cc) * 64) + h) * 64 + ww];
    *(u16x8*)&t[cc][ww] = v;
  }
  __syncthreads();
#pragma unroll
  for (int i = 0; i < 2; ++i) {
    int idx = i * 256 + tid;
    int ww = idx >> 3, cc = (idx & 7) * 8;
    u16x8 v;
#pragma unroll
    for (int j = 0; j < 8; ++j) v[j] = t[cc + j][ww];
    *(u16x8*)&xpad[(((size_t)b * 66 + h + 1) * 66 + ww + 1) * 2048 + c0 + cc] = v;
  }
}

// ---------------- generic bf16 transpose (R,C)->(C,R) per batch ----------------
__global__ __launch_bounds__(256) void transpose64(const u16* __restrict__ src, u16* __restrict__ dst,
                                                   int R, int C) {
  __shared__ u16 t[64][72];
  int r0 = blockIdx.x * 64, c0 = blockIdx.y * 64;
  const u16* s = src + (size_t)blockIdx.z * R * C;
  u16* d = dst + (size_t)blockIdx.z * R * C;
  int tid = threadIdx.x;
#pragma unroll
  for (int i = 0; i < 2; ++i) {
    int idx = i * 256 + tid;
    int rr = idx >> 3, cc = (idx & 7) * 8;
    u16x8 v = *(const u16x8*)&s[(size_t)(r0 + rr) * C + c0 + cc];
    *(u16x8*)&t[rr][cc] = v;
  }
  __syncthreads();
#pragma unroll
  for (int i = 0; i < 2; ++i) {
    int idx = i * 256 + tid;
    int cc = idx >> 3, rr = (idx & 7) * 8;
    u16x8 v;
#pragma unroll
    for (int j = 0; j < 8; ++j) v[j] = t[rr + j][cc];
    *(u16x8*)&d[(size_t)(c0 + cc) * R + r0 + rr] = v;
  }
}

// ---------------- unified NT GEMM: C[m,n] = sum_k A[m,k]*B[n,k] ----------------
// EPI: 0 = bf16 store (+bias, *rowscale) ; 1 = bf16 transposed store (+bias,*rowscale)
//      2 = fp32 store ; 3 = alpha*acc + residual -> padded NHWC bf16 store
struct GemmP {
  const u16* A; const u16* B;
  long aBatch, bBatch;
  int M, N, K;
  u16* out; long outBatch; int ldOut;
  const u16* bias;
  const u16* rowscale;
  const u16* residual; long resBatch; int ldRes;
  const u16* alphaPtr;
  float* outF; long outFBatch;
};

template <int BM, int BN, int EPI>
__global__ __launch_bounds__(256) void gemm_nt(GemmP p) {
  __shared__ u16 lA[BM * 32], lB[BN * 32];
  const int tid = threadIdx.x;
  const int bz = blockIdx.z;
  const int m0 = blockIdx.x * BM, n0 = blockIdx.y * BN;
  const u16* A = p.A + (size_t)bz * p.aBatch;
  const u16* Bp = p.B + (size_t)bz * p.bBatch;
  const int wave = tid >> 6, lane = tid & 63;
  const int quad = lane >> 4, r16 = lane & 15;
  const int wm = (wave >> 1) * (BM / 2), wn = (wave & 1) * (BN / 2);
  constexpr int TM = BM / 32, TN = BN / 32;
  f32x4 acc[TM][TN] = {};
  const int srow = tid >> 2, sch = (tid & 3) * 8;
  const int K = p.K;
  for (int k0 = 0; k0 < K; k0 += 32) {
    u16x8 ra[BM / 64], rb[BN / 64];
#pragma unroll
    for (int i = 0; i < BM / 64; ++i)
      ra[i] = *(const u16x8*)&A[(size_t)(m0 + i * 64 + srow) * K + k0 + sch];
#pragma unroll
    for (int i = 0; i < BN / 64; ++i)
      rb[i] = *(const u16x8*)&Bp[(size_t)(n0 + i * 64 + srow) * K + k0 + sch];
    __syncthreads();
#pragma unroll
    for (int i = 0; i < BM / 64; ++i) *(u16x8*)&lA[i * 2048 + tid * 8] = ra[i];
#pragma unroll
    for (int i = 0; i < BN / 64; ++i) *(u16x8*)&lB[i * 2048 + tid * 8] = rb[i];
    __syncthreads();
    s16x8 av[TM], bv[TN];
#pragma unroll
    for (int t = 0; t < TM; ++t) av[t] = *(const s16x8*)&lA[(wm + t * 16 + r16) * 32 + quad * 8];
#pragma unroll
    for (int t = 0; t < TN; ++t) bv[t] = *(const s16x8*)&lB[(wn + t * 16 + r16) * 32 + quad * 8];
#pragma unroll
    for (int i = 0; i < TM; ++i)
#pragma unroll
      for (int j = 0; j < TN; ++j)
        acc[i][j] = __builtin_amdgcn_mfma_f32_16x16x32_bf16(av[i], bv[j], acc[i][j], 0, 0, 0);
  }
  float alpha = 0.f;
  if (EPI == 3) alpha = bf2f(p.alphaPtr[0]);
#pragma unroll
  for (int i = 0; i < TM; ++i) {
#pragma unroll
    for (int j = 0; j < TN; ++j) {
      const int nn = n0 + wn + j * 16 + r16;
      float bia = 0.f;
      if ((EPI == 0 || EPI == 1) && p.bias) bia = bf2f(p.bias[nn]);
#pragma unroll
      for (int r = 0; r < 4; ++r) {
        const int mm = m0 + wm + i * 16 + quad * 4 + r;
        float v = acc[i][j][r];
        if (EPI == 0) {
          v += bia;
          if (p.rowscale) v *= bf2f(p.rowscale[mm]);
          p.out[(size_t)bz * p.outBatch + (size_t)mm * p.ldOut + nn] = f2bf(v);
        } else if (EPI == 1) {
          v += bia;
          if (p.rowscale) v *= bf2f(p.rowscale[mm]);
          p.out[(size_t)bz * p.outBatch + (size_t)nn * p.ldOut + mm] = f2bf(v);
        } else if (EPI == 2) {
          p.outF[(size_t)bz * p.outFBatch + (size_t)mm * p.ldOut + nn] = v;
        } else {
          float res = bf2f(p.residual[(size_t)bz * p.resBatch + (size_t)mm * p.ldRes + nn]);
          v = alpha * v + res;
          const int py = mm >> 6, px = mm & 63;
          p.out[(size_t)bz * p.outBatch + ((size_t)(py + 1) * 66 + (px + 1)) * p.ldOut + nn] = f2bf(v);
        }
      }
    }
  }
}

// ---------------- fused 3-conv 3x3 (implicit GEMM) + BN + ReLU, NHWC padded input ----------------
// blockIdx.z in [0,6): ci = z>>1 selects conv (input/weights/output), b = z&1 batch.
struct Conv3P {
  const u16* in[3];
  const u16* wr[3];
  u16* out[3];
  const float* bn;   // conv ci: scale = bn[ci*1024 + n], shift = bn[ci*1024 + 512 + n]
};

template <int CIN>
__global__ __launch_bounds__(256) void conv3x3_k(Conv3P p) {
  __shared__ u16 lA[4096], lB[4096];
  const int tid = threadIdx.x;
  const int z = blockIdx.z, ci = z >> 1, b = z & 1;
  const int m0 = blockIdx.x * 128, n0 = blockIdx.y * 128;
  const u16* __restrict__ xin = p.in[ci];
  const u16* __restrict__ wr = p.wr[ci];
  const int wave = tid >> 6, lane = tid & 63;
  const int quad = lane >> 4, r16 = lane & 15;
  const int wm = (wave >> 1) * 64, wn = (wave & 1) * 64;
  f32x4 acc[4][4] = {};
  const int srow = tid >> 2, sch = (tid & 3) * 8;
  const int p0 = m0 + srow, p1 = p0 + 64;
  const size_t a0 = (((size_t)b * 66 + (p0 >> 6)) * 66 + (p0 & 63)) * CIN + sch;
  const size_t a1 = (((size_t)b * 66 + (p1 >> 6)) * 66 + (p1 & 63)) * CIN + sch;
  const size_t b0 = ((size_t)(n0 + srow) * 9) * CIN + sch;
  const size_t b1 = ((size_t)(n0 + 64 + srow) * 9) * CIN + sch;
  for (int kh = 0; kh < 3; ++kh) {
    for (int kw = 0; kw < 3; ++kw) {
      const size_t soff = ((size_t)kh * 66 + kw) * CIN;
      const size_t woff = (size_t)(kh * 3 + kw) * CIN;
      for (int c = 0; c < CIN; c += 32) {
        u16x8 ra0 = *(const u16x8*)&xin[a0 + soff + c];
        u16x8 ra1 = *(const u16x8*)&xin[a1 + soff + c];
        u16x8 rb0 = *(const u16x8*)&wr[b0 + woff + c];
        u16x8 rb1 = *(const u16x8*)&wr[b1 + woff + c];
        __syncthreads();
        *(u16x8*)&lA[tid * 8] = ra0;
        *(u16x8*)&lA[2048 + tid * 8] = ra1;
        *(u16x8*)&lB[tid * 8] = rb0;
        *(u16x8*)&lB[2048 + tid * 8] = rb1;
        __syncthreads();
        s16x8 av[4], bv[4];
#pragma unroll
        for (int t = 0; t < 4; ++t) av[t] = *(const s16x8*)&lA[(wm + t * 16 + r16) * 32 + quad * 8];
#pragma unroll
        for (int t = 0; t < 4; ++t) bv[t] = *(const s16x8*)&lB[(wn + t * 16 + r16) * 32 + quad * 8];
#pragma unroll
        for (int i = 0; i < 4; ++i)
#pragma unroll
          for (int j = 0; j < 4; ++j)
            acc[i][j] = __builtin_amdgcn_mfma_f32_16x16x32_bf16(av[i], bv[j], acc[i][j], 0, 0, 0);
      }
    }
  }
  u16* __restrict__ out = p.out[ci];
  const float* bnS = p.bn + ci * 1024;
#pragma unroll
  for (int i = 0; i < 4; ++i) {
#pragma unroll
    for (int j = 0; j < 4; ++j) {
      const int nn = n0 + wn + j * 16 + r16;
      const float s = bnS[nn], sh = bnS[512 + nn];
#pragma unroll
      for (int r = 0; r < 4; ++r) {
        const int mm = m0 + wm + i * 16 + quad * 4 + r;
        float v = fmaxf(acc[i][j][r] * s + sh, 0.f);
        out[((size_t)b * 4096 + mm) * 512 + nn] = f2bf(v);
      }
    }
  }
}

// ---------------- softmax over rows of 4096 (fp32 in, bf16 out) ----------------
__global__ __launch_bounds__(256) void softmax4096(const float* __restrict__ S, u16* __restrict__ P) {
  int row = blockIdx.x, tid = threadIdx.x;
  const float* sr = S + (size_t)row * 4096;
  f32x4 v[4];
  float mx = -3.4e38f;
#pragma unroll
  for (int i = 0; i < 4; ++i) {
    v[i] = *(const f32x4*)&sr[(i * 256 + tid) * 4];
    mx = fmaxf(mx, fmaxf(fmaxf(v[i][0], v[i][1]), fmaxf(v[i][2], v[i][3])));
  }
  __shared__ float red[8];
  int wave = tid >> 6, lane = tid & 63;
  for (int off = 32; off; off >>= 1) mx = fmaxf(mx, __shfl_xor(mx, off));
  if (lane == 0) red[wave] = mx;
  __syncthreads();
  mx = fmaxf(fmaxf(red[0], red[1]), fmaxf(red[2], red[3]));
  float sum = 0.f;
#pragma unroll
  for (int i = 0; i < 4; ++i)
#pragma unroll
    for (int j = 0; j < 4; ++j) { float e = __expf(v[i][j] - mx); v[i][j] = e; sum += e; }
  for (int off = 32; off; off >>= 1) sum += __shfl_xor(sum, off);
  if (lane == 0) red[4 + wave] = sum;
  __syncthreads();
  sum = red[4] + red[5] + red[6] + red[7];
  float inv = 1.f / sum;
  u16* pr = P + (size_t)row * 4096;
#pragma unroll
  for (int i = 0; i < 4; ++i) {
    u16x4 ov;
#pragma unroll
    for (int j = 0; j < 4; ++j) ov[j] = f2bf(v[i][j] * inv);
    *(u16x4*)&pr[(i * 256 + tid) * 4] = ov;
  }
}

// ---------------- CAM softmax: L = rowmax - S, softmax(L); rows of 512 ----------------
__global__ __launch_bounds__(256) void softmax_cam(const float* __restrict__ S, u16* __restrict__ P) {
  int row = blockIdx.x, tid = threadIdx.x;
  const float* sr = S + (size_t)row * 512;
  float a = sr[tid], b = sr[tid + 256];
  __shared__ float red[12];
  int wave = tid >> 6, lane = tid & 63;
  float mx = fmaxf(a, b);
  for (int off = 32; off; off >>= 1) mx = fmaxf(mx, __shfl_xor(mx, off));
  if (lane == 0) red[wave] = mx;
  __syncthreads();
  float M1 = fmaxf(fmaxf(red[0], red[1]), fmaxf(red[2], red[3]));
  float mn = fminf(a, b);
  for (int off = 32; off; off >>= 1) mn = fminf(mn, __shfl_xor(mn, off));
  if (lane == 0) red[4 + wave] = mn;
  __syncthreads();
  float m2 = M1 - fminf(fminf(red[4], red[5]), fminf(red[6], red[7]));
  float e0 = __expf((M1 - a) - m2), e1 = __expf((M1 - b) - m2);
  float sum = e0 + e1;
  for (int off = 32; off; off >>= 1) sum += __shfl_xor(sum, off);
  if (lane == 0) red[8 + wave] = sum;
  __syncthreads();
  sum = red[8] + red[9] + red[10] + red[11];
  float inv = 1.f / sum;
  P[(size_t)row * 512 + tid] = f2bf(e0 * inv);
  P[(size_t)row * 512 + tid + 256] = f2bf(e1 * inv);
}

// ---------------- final three 19-class 1x1 convs (writes NCHW d_out, dtype per flag) ----------------
__global__ __launch_bounds__(256) void final_out_k(const u16* __restrict__ fp2, const u16* __restrict__ fc2,
                                                   const u16* __restrict__ fv2,
                                                   const u16* ow, const u16* ob, const u16* pw,
                                                   const u16* pb, const u16* cw, const u16* cb,
                                                   void* __restrict__ out, const int* __restrict__ flag) {
  __shared__ float wl[19 * 512];
  int tid = threadIdx.x, which = blockIdx.y;
  const u16* W = which == 0 ? ow : which == 1 ? pw : cw;
  const u16* Bb = which == 0 ? ob : which == 1 ? pb : cb;
  for (int i = tid; i < 19 * 512; i += 256) wl[i] = bf2f(W[i]);
  __syncthreads();
  int pix = blockIdx.x * 256 + threadIdx.x;
  size_t rb = (size_t)pix * 512;
  float acc[19];
#pragma unroll
  for (int o = 0; o < 19; ++o) acc[o] = 0.f;
  for (int c = 0; c < 512; c += 8) {
    float xs[8];
    if (which == 0) {
      u16x8 a = *(const u16x8*)&fp2[rb + c];
      u16x8 d = *(const u16x8*)&fc2[rb + c];
      u16x8 e = *(const u16x8*)&fv2[rb + c];
#pragma unroll
      for (int j = 0; j < 8; ++j) xs[j] = bf2f(a[j]) + bf2f(d[j]) + bf2f(e[j]);
    } else {
      const u16* src = which == 1 ? fp2 : fc2;
      u16x8 a = *(const u16x8*)&src[rb + c];
#pragma unroll
      for (int j = 0; j < 8; ++j) xs[j] = bf2f(a[j]);
    }
#pragma unroll
    for (int o = 0; o < 19; ++o) {
      const float* wv = &wl[o * 512 + c];
#pragma unroll
      for (int j = 0; j < 8; ++j) acc[o] += xs[j] * wv[j];
    }
  }
  int b = pix >> 12, n = pix & 4095;
  const int isF32 = *flag;
#pragma unroll
  for (int o = 0; o < 19; ++o) {
    size_t idx = (size_t)which * 155648 + ((size_t)(b * 19 + o)) * 4096 + n;
    float v = acc[o] + bf2f(Bb[o]);
    if (isF32) ((float*)out)[idx] = v;
    else ((u16*)out)[idx] = f2bf(v);
  }
}

// ---------------- workspace layout (bytes) ----------------
// FIX (R6): QT/KT are 2 batches x 4096 x 64 bf16 = 1,048,576 B EACH (round-4 layout
// gave them 524,288 B -> q/k batch-1 overflowed into KT/VT: the 0.459 absmax).
static const size_t OFF_XPAD  = 0;            // 35,684,352
static const size_t OFF_WR1A  = 35684352;     // 18,874,368
static const size_t OFF_WR1B  = 54558720;     // 18,874,368
static const size_t OFF_WR1C  = 73433088;     // 18,874,368
static const size_t OFF_ARENA = 92307456;     // 33,554,432  (x conversion; then per-weight staging)
static const size_t OFF_S     = 0;            // 67,108,864  (PAM overlay; phase-1 region dead)
static const size_t OFF_P     = 67108864;     // 33,554,432  (PAM overlay)
static const size_t OFF_ARENA2= 0;            //  4,718,592  (stage-2 wconv staging, after PAM/CAM)
static const size_t OFF_FP1   = 125861888;    //  8,388,608
static const size_t OFF_FC1   = 134250496;    //  8,388,608
static const size_t OFF_FV1   = 142639104;    //  8,388,608
static const size_t OFF_FC1T  = 151027712;    //  8,388,608  (dead after CAM S-gemm)
static const size_t OFF_QT    = 159416320;    //  1,048,576  (dead after PAM)
static const size_t OFF_KT    = 160464896;    //  1,048,576  (dead after PAM)
static const size_t OFF_VT    = 161513472;    //  8,388,608  (dead after PAM)
static const size_t OFF_WRSA  = 151027712;    //  4,718,592  (overlay FC1T head; after CAM)
static const size_t OFF_WRSB  = 155746304;    //  4,718,592  (overlay FC1T tail + QT)
static const size_t OFF_WRSC  = 161513472;    //  4,718,592  (overlay VT)
static const size_t OFF_PADP  = 169902080;    //  8,921,088
static const size_t OFF_PADC  = 178823168;    //  8,921,088
static const size_t OFF_PADV  = 187744256;    //  8,921,088
static const size_t OFF_FP2   = 125861888;    // overlay FP1 (dead after PAM-P)
static const size_t OFF_FC2   = 134250496;    // overlay FC1 (dead after CAM)
static const size_t OFF_FV2   = 142639104;    // overlay FV1 (dead after PAM-V)
static const size_t OFF_SC    = 196665344;    //  2,097,152
static const size_t OFF_PC    = 198762496;    //  1,048,576
static const size_t OFF_BN    = 199811072;    //     24,576
static const size_t OFF_FLAG  = 199835648;    //        256
static const size_t OFF_SMALL = 199835904;    //  1,404,704
// small-block element offsets (u16):
static const size_t SO_CBN    = 0;
static const size_t SO_PWB    = 12288;
static const size_t SO_PBB    = 45056;
static const size_t SO_PWC    = 45120;
static const size_t SO_PBC    = 77888;
static const size_t SO_PWD    = 77952;
static const size_t SO_PBD    = 340096;
static const size_t SO_PAL    = 340608;
static const size_t SO_CBETA  = 340624;
static const size_t SO_VWB    = 340640;
static const size_t SO_VBB    = 373408;
static const size_t SO_VWC    = 373472;
static const size_t SO_VBC    = 406240;
static const size_t SO_VWD    = 406304;
static const size_t SO_VBD    = 668448;
static const size_t SO_VAL    = 668960;
static const size_t SO_OW     = 668976;
static const size_t SO_OB     = 678704;
static const size_t SO_PW3    = 678736;
static const size_t SO_PB3    = 688464;
static const size_t SO_CW3    = 688496;
static const size_t SO_CB3    = 698224;
static const size_t SO_LFM    = 698256;
static const size_t SO_END    = 702352;
static const size_t WS_NEEDED = OFF_SMALL + SO_END * 2;  // 201,240,608

extern "C" void kernel_launch(void* const* d_in, const int* in_sizes, int n_in,
                              void* d_out, int out_size, void* d_ws, size_t ws_size,
                              hipStream_t stream) {
  if (ws_size < WS_NEEDED) return;
  (void)in_sizes; (void)n_in; (void)out_size;

  char* ws = (char*)d_ws;
  u16* xpad   = (u16*)(ws + OFF_XPAD);
  u16* wr1a   = (u16*)(ws + OFF_WR1A);
  u16* wr1b   = (u16*)(ws + OFF_WR1B);
  u16* wr1c   = (u16*)(ws + OFF_WR1C);
  u16* arena  = (u16*)(ws + OFF_ARENA);
  u16* arena2 = (u16*)(ws + OFF_ARENA2);
  float* S    = (float*)(ws + OFF_S);
  u16* P      = (u16*)(ws + OFF_P);
  u16* fp1    = (u16*)(ws + OFF_FP1);
  u16* fc1    = (u16*)(ws + OFF_FC1);
  u16* fv1    = (u16*)(ws + OFF_FV1);
  u16* fc1T   = (u16*)(ws + OFF_FC1T);
  u16* qt     = (u16*)(ws + OFF_QT);
  u16* kt     = (u16*)(ws + OFF_KT);
  u16* vT     = (u16*)(ws + OFF_VT);
  u16* wrsa   = (u16*)(ws + OFF_WRSA);
  u16* wrsb   = (u16*)(ws + OFF_WRSB);
  u16* wrsc   = (u16*)(ws + OFF_WRSC);
  u16* padP   = (u16*)(ws + OFF_PADP);
  u16* padC   = (u16*)(ws + OFF_PADC);
  u16* padV   = (u16*)(ws + OFF_PADV);
  u16* fp2    = (u16*)(ws + OFF_FP2);
  u16* fc2    = (u16*)(ws + OFF_FC2);
  u16* fv2    = (u16*)(ws + OFF_FV2);
  float* Sc   = (float*)(ws + OFF_SC);
  u16* Pc     = (u16*)(ws + OFF_PC);
  float* bnb  = (float*)(ws + OFF_BN);
  int* flag   = (int*)(ws + OFF_FLAG);
  u16* sm     = (u16*)(ws + OFF_SMALL);

  // ---- dtype detect + canonicalize inputs ----
  detect_dtype<<<1, 256, 0, stream>>>((const u16*)d_in[0], flag);
  auto cv = [&](int i, u16* dst, int n) {
    convert_in<<<(n + 255) / 256, 256, 0, stream>>>(d_in[i], dst, n, flag);
  };
  cv(3,  sm + SO_CBN + 0 * 2048, 2048);
  cv(7,  sm + SO_CBN + 1 * 2048, 2048);
  cv(11, sm + SO_CBN + 2 * 2048, 2048);
  cv(5,  sm + SO_CBN + 3 * 2048, 2048);
  cv(9,  sm + SO_CBN + 4 * 2048, 2048);
  cv(13, sm + SO_CBN + 5 * 2048, 2048);
  cv(14, sm + SO_PWB, 32768);  cv(15, sm + SO_PBB, 64);
  cv(16, sm + SO_PWC, 32768);  cv(17, sm + SO_PBC, 64);
  cv(18, sm + SO_PWD, 262144); cv(19, sm + SO_PBD, 512);
  cv(20, sm + SO_PAL, 1);      cv(21, sm + SO_CBETA, 1);
  cv(22, sm + SO_VWB, 32768);  cv(23, sm + SO_VBB, 64);
  cv(24, sm + SO_VWC, 32768);  cv(25, sm + SO_VBC, 64);
  cv(26, sm + SO_VWD, 262144); cv(27, sm + SO_VBD, 512);
  cv(28, sm + SO_VAL, 1);
  cv(29, sm + SO_OW, 9728);    cv(30, sm + SO_OB, 19);
  cv(31, sm + SO_PW3, 9728);   cv(32, sm + SO_PB3, 19);
  cv(33, sm + SO_CW3, 9728);   cv(34, sm + SO_CB3, 19);
  cv(1,  sm + SO_LFM, 4096);

  bn_prep<<<6, 512, 0, stream>>>(sm + SO_CBN, bnb);

  // ---- x -> padded NHWC ----
  cv(0, arena, 16777216);
  hipMemsetAsync(xpad, 0, 35684352, stream);
  pad_nchw<<<dim3(32, 64, 2), 256, 0, stream>>>(arena, xpad);

  // ---- stage-1 weights: convert + repack all three, then ONE fused conv dispatch ----
  cv(2, arena, 9437184);
  repack_w3<<<4608, 256, 0, stream>>>(arena, wr1a, 2048, 11);
  cv(6, arena, 9437184);
  repack_w3<<<4608, 256, 0, stream>>>(arena, wr1b, 2048, 11);
  cv(10, arena, 9437184);
  repack_w3<<<4608, 256, 0, stream>>>(arena, wr1c, 2048, 11);
  {
    Conv3P c{};
    c.in[0] = xpad; c.in[1] = xpad; c.in[2] = xpad;
    c.wr[0] = wr1a; c.wr[1] = wr1b; c.wr[2] = wr1c;
    c.out[0] = fp1; c.out[1] = fc1; c.out[2] = fv1;
    c.bn = bnb;
    conv3x3_k<2048><<<dim3(32, 4, 6), 256, 0, stream>>>(c);
  }

  // ---- PAM (shared for pam / vfam) ----
  auto runPam = [&](const u16* src, const u16* wb, const u16* bb, const u16* wck, const u16* bck,
                    const u16* wd, const u16* bd, const u16* alphaP, const u16* rs, u16* padOut) {
    GemmP g{};
    g.A = src; g.aBatch = 2097152; g.B = wb; g.bBatch = 0; g.M = 4096; g.N = 64; g.K = 512;
    g.out = qt; g.outBatch = 262144; g.ldOut = 64; g.bias = bb; g.rowscale = rs;
    gemm_nt<64, 64, 0><<<dim3(64, 1, 2), 256, 0, stream>>>(g);
    g.B = wck; g.bias = bck; g.out = kt;
    gemm_nt<64, 64, 0><<<dim3(64, 1, 2), 256, 0, stream>>>(g);
    GemmP gv{};
    gv.A = src; gv.aBatch = 2097152; gv.B = wd; gv.bBatch = 0; gv.M = 4096; gv.N = 512; gv.K = 512;
    gv.out = vT; gv.outBatch = 2097152; gv.ldOut = 4096; gv.bias = bd; gv.rowscale = rs;
    gemm_nt<64, 128, 1><<<dim3(64, 4, 2), 256, 0, stream>>>(gv);
    hipMemsetAsync(padOut, 0, 8921088, stream);
    for (int b = 0; b < 2; ++b) {
      GemmP gs{};
      gs.A = qt + (size_t)b * 262144; gs.B = kt + (size_t)b * 262144;
      gs.M = 4096; gs.N = 4096; gs.K = 64;
      gs.outF = S; gs.outFBatch = 0; gs.ldOut = 4096;
      gemm_nt<128, 128, 2><<<dim3(32, 32, 1), 256, 0, stream>>>(gs);
      softmax4096<<<4096, 256, 0, stream>>>(S, P);
      GemmP gf{};
      gf.A = P; gf.aBatch = 0; gf.B = vT + (size_t)b * 2097152; gf.bBatch = 0;
      gf.M = 4096; gf.N = 512; gf.K = 4096;
      gf.out = padOut + (size_t)b * 2230272; gf.outBatch = 0; gf.ldOut = 512;
      gf.residual = src + (size_t)b * 2097152; gf.resBatch = 0; gf.ldRes = 512;
      gf.alphaPtr = alphaP;
      gemm_nt<64, 64, 3><<<dim3(64, 8, 1), 256, 0, stream>>>(gf);
    }
  };
  runPam(fp1, sm + SO_PWB, sm + SO_PBB, sm + SO_PWC, sm + SO_PBC, sm + SO_PWD, sm + SO_PBD,
         sm + SO_PAL, nullptr, padP);
  runPam(fv1, sm + SO_VWB, sm + SO_VBB, sm + SO_VWC, sm + SO_VBC, sm + SO_VWD, sm + SO_VBD,
         sm + SO_VAL, sm + SO_LFM, padV);

  // ---- CAM ----
  transpose64<<<dim3(64, 8, 2), 256, 0, stream>>>(fc1, fc1T, 4096, 512);
  {
    GemmP g{};
    g.A = fc1T; g.aBatch = 2097152; g.B = fc1T; g.bBatch = 2097152;
    g.M = 512; g.N = 512; g.K = 4096;
    g.outF = Sc; g.outFBatch = 262144; g.ldOut = 512;
    gemm_nt<64, 64, 2><<<dim3(8, 8, 2), 256, 0, stream>>>(g);
  }
  softmax_cam<<<1024, 256, 0, stream>>>(Sc, Pc);
  hipMemsetAsync(padC, 0, 8921088, stream);
  {
    GemmP g{};
    g.A = fc1; g.aBatch = 2097152; g.B = Pc; g.bBatch = 262144;
    g.M = 4096; g.N = 512; g.K = 512;
    g.out = padC; g.outBatch = 2230272; g.ldOut = 512;
    g.residual = fc1; g.resBatch = 2097152; g.ldRes = 512;
    g.alphaPtr = sm + SO_CBETA;
    gemm_nt<128, 128, 3><<<dim3(32, 4, 2), 256, 0, stream>>>(g);
  }

  // ---- stage-2 weights: convert + repack, then ONE fused conv dispatch ----
  cv(4, arena2, 2359296);
  repack_w3<<<1152, 256, 0, stream>>>(arena2, wrsa, 512, 9);
  cv(8, arena2, 2359296);
  repack_w3<<<1152, 256, 0, stream>>>(arena2, wrsb, 512, 9);
  cv(12, arena2, 2359296);
  repack_w3<<<1152, 256, 0, stream>>>(arena2, wrsc, 512, 9);
  {
    Conv3P c{};
    c.in[0] = padP; c.in[1] = padC; c.in[2] = padV;
    c.wr[0] = wrsa; c.wr[1] = wrsb; c.wr[2] = wrsc;
    c.out[0] = fp2; c.out[1] = fc2; c.out[2] = fv2;
    c.bn = bnb + 3 * 1024;
    conv3x3_k<512><<<dim3(32, 4, 6), 256, 0, stream>>>(c);
  }

  // ---- final 1x1 convs -> d_out (fusion_out, p_out, c_out) ----
  final_out_k<<<dim3(32, 3), 256, 0, stream>>>(fp2, fc2, fv2, sm + SO_OW, sm + SO_OB,
                                               sm + SO_PW3, sm + SO_PB3, sm + SO_CW3, sm + SO_CB3,
                                               d_out, flag);
}